// Round 8
// baseline (91.487 us; speedup 1.0000x reference)
//
#include <hip/hip_runtime.h>
#include <math.h>

// BoundaryDistanceLoss — H=W=1024 binary masks (float 0/1).
// edges = seg - erode3x3(seg); exact EDT of edges; loss =
// sigmoid((mean(target_edges*pred_dt) + mean(pred_edges*target_dt))/2).
//
// R7->R8: fixed the winf LDS race (all threads stored winf, clobbering the
// winner flag -> finalize never ran -> out=0). Also made the empty-row
// sentinel reference-exact (g = 1e6 - j, matching jax cummin path; dead for
// this input but correct). Structure otherwise identical to R7:
// 2 nodes, u16 g, bit-packed transposed edges, two-level done-counters.
//
// ws layout: gp (2MB u16) | gt (2MB) | epb (128KB u16) | etb (128KB)
//            | partial (4KB f32) | cnts (17 u32: 16 L1 + 1 L2)
// g[r][j] = row-distance to nearest edge (65535 => empty row, g=1e6-j)

#define HW 1024
#define RMIN_SENT (1 << 30)
#define WIN 8
#define RPB 128
#define KROWS (RPB + 2 * WIN)   // 144
#define HS_STRIDE 17

// ---------------- Kernel A: edges + row-pass (one row per wave) ----------------
// grid (256, 2), block 256 = 4 waves = 4 rows. Lane owns 16 contiguous cols.
__global__ __launch_bounds__(256)
void k_rows(const float* __restrict__ pred, const float* __restrict__ targ,
            unsigned short* __restrict__ gp, unsigned short* __restrict__ gt,
            unsigned short* __restrict__ epb, unsigned short* __restrict__ etb,
            unsigned* __restrict__ cnts)
{
    const int t    = threadIdx.x;
    const int lane = t & 63;
    const int wv   = t >> 6;
    const int r    = blockIdx.x * 4 + wv;     // row 0..1023
    const int m    = blockIdx.y;              // image 0=pred 1=target
    const float* __restrict__ seg = m ? targ : pred;
    unsigned short* __restrict__ gout = m ? gt : gp;
    unsigned short* __restrict__ ebout = m ? etb : epb;

    if (blockIdx.x == 0 && m == 0 && t < 17) cnts[t] = 0u;  // k_cols runs after

    const int c0 = lane * 16;                 // first global col of this lane

    float cs[16], cm[16], cp[16];
    #pragma unroll
    for (int q = 0; q < 4; ++q)
        *(float4*)&cs[q * 4] = *(const float4*)&seg[r * HW + c0 + q * 4];
    #pragma unroll
    for (int q = 0; q < 4; ++q) {
        *(float4*)&cm[q * 4] = make_float4(0.f, 0.f, 0.f, 0.f);
        *(float4*)&cp[q * 4] = make_float4(0.f, 0.f, 0.f, 0.f);
    }
    if (r > 0) {
        #pragma unroll
        for (int q = 0; q < 4; ++q)
            *(float4*)&cm[q * 4] = *(const float4*)&seg[(r - 1) * HW + c0 + q * 4];
    }
    if (r < HW - 1) {
        #pragma unroll
        for (int q = 0; q < 4; ++q)
            *(float4*)&cp[q * 4] = *(const float4*)&seg[(r + 1) * HW + c0 + q * 4];
    }

    // bitmasks over the lane's 16 columns
    unsigned s_bits = 0, va_bits = 0;
    #pragma unroll
    for (int x = 0; x < 16; ++x) {
        const unsigned s  = (cs[x] != 0.f) ? 1u : 0u;
        const unsigned va = (cs[x] != 0.f && cm[x] != 0.f && cp[x] != 0.f) ? 1u : 0u;
        s_bits  |= s  << x;
        va_bits |= va << x;
    }

    // neighbor bits across lanes (image border -> 0, matches zero padding)
    const unsigned vprev = __shfl_up(va_bits, 1);
    const unsigned vnext = __shfl_down(va_bits, 1);
    const unsigned lbit = (lane == 0)  ? 0u : ((vprev >> 15) & 1u);
    const unsigned rbit = (lane == 63) ? 0u : (vnext & 1u);

    // eroded_x = va_{x-1} & va_x & va_{x+1} via an 18-bit window
    const unsigned w18 = (va_bits << 1) | lbit | (rbit << 17);
    const unsigned eroded = w18 & (w18 >> 1) & (w18 >> 2);
    const unsigned edge = s_bits & ~eroded & 0xFFFFu;

    // edge bits: transposed layout ebout[wordcol*1024 + r] for coalesced consume
    ebout[lane * HW + r] = (unsigned short)edge;

    // lane aggregates: last/first set feature col in this lane
    const int lane_last  = edge ? (c0 + 31 - __clz(edge)) : -1;
    const int lane_first = edge ? (c0 + __ffs(edge) - 1)  : RMIN_SENT;

    // wave scans (inclusive), then exclusive carries
    int Li = lane_last;
    #pragma unroll
    for (int off = 1; off < 64; off <<= 1) {
        const int v = __shfl_up(Li, off);
        if (lane >= off) Li = max(Li, v);
    }
    int Ri = lane_first;
    #pragma unroll
    for (int off = 1; off < 64; off <<= 1) {
        const int v = __shfl_down(Ri, off);
        if (lane + off < 64) Ri = min(Ri, v);
    }
    int carryL = __shfl_up(Li, 1);   if (lane == 0)  carryL = -1;
    int carryR = __shfl_down(Ri, 1); if (lane == 63) carryR = RMIN_SENT;

    // per-column nearest feature; g as u16 (65535 == empty row => g = 1e6 - j)
    unsigned short gv[16];
    #pragma unroll
    for (int x = 0; x < 16; ++x) {
        const unsigned ble = edge & ((2u << x) - 1u);   // bits 0..x
        const int L = ble ? (c0 + 31 - __clz(ble)) : carryL;
        const unsigned bge = edge >> x;                 // bits x..15
        const int R = bge ? (c0 + x + __ffs(bge) - 1) : carryR;
        const int j = c0 + x;
        int g;
        if (L < 0 && R >= RMIN_SENT)      g = 65535;          // empty row sentinel
        else if (L < 0)                   g = R - j;
        else if (R >= RMIN_SENT)          g = j - L;
        else                              g = min(j - L, R - j);
        gv[x] = (unsigned short)g;
    }
    unsigned wpk[8];
    #pragma unroll
    for (int k2 = 0; k2 < 8; ++k2)
        wpk[k2] = (unsigned)gv[2 * k2] | ((unsigned)gv[2 * k2 + 1] << 16);
    uint4 st0, st1;
    st0.x = wpk[0]; st0.y = wpk[1]; st0.z = wpk[2]; st0.w = wpk[3];
    st1.x = wpk[4]; st1.y = wpk[5]; st1.z = wpk[6]; st1.w = wpk[7];
    *(uint4*)&gout[r * HW + c0]     = st0;
    *(uint4*)&gout[r * HW + c0 + 8] = st1;
}

// ------------- Kernel B: column EDT (windowed, exact) + finalize -------------
// grid (64 col-tiles, 8 row-chunks, 2 images) = 1024 blocks, block 256.
__global__ __launch_bounds__(256)
void k_cols(const unsigned short* __restrict__ gp, const unsigned short* __restrict__ gt,
            const unsigned short* __restrict__ epb, const unsigned short* __restrict__ etb,
            float* __restrict__ partial, unsigned* __restrict__ cnts,
            float* __restrict__ out)
{
    const int j0 = blockIdx.x * 16;
    const int i0 = blockIdx.y * RPB;
    const int m  = blockIdx.z;
    const unsigned short* __restrict__ gg = m ? gt : gp;
    const unsigned short* __restrict__ ewb = m ? epb : etb;  // OTHER image's edges

    __shared__ float hs[KROWS * HS_STRIDE];
    __shared__ unsigned short esb[RPB];
    __shared__ float wsum[4];
    __shared__ int winf;

    // stage h = g^2 + k^2 (g from u16; sentinel -> g = 1e6 - j, ref-exact)
    for (int idx = threadIdx.x; idx < KROWS * 16; idx += 256) {
        const int kk = idx >> 4, jc = idx & 15;
        const int gk = i0 - WIN + kk;
        float v = 1e30f;
        if ((unsigned)gk < (unsigned)HW) {
            const unsigned gu = gg[gk * HW + j0 + jc];
            float gf = (gu == 65535u) ? (1e6f - (float)(j0 + jc)) : (float)gu;
            v = fmaf(gf, gf, (float)(gk * gk));
        }
        hs[kk * HS_STRIDE + jc] = v;
    }
    if (threadIdx.x < RPB)
        esb[threadIdx.x] = ewb[(j0 >> 4) * HW + i0 + threadIdx.x];
    __syncthreads();

    const int jj = threadIdx.x & 15;
    const int iw = threadIdx.x >> 4;   // 0..15, each owns 8 rows
    float lsum = 0.f;

    #pragma unroll
    for (int g = 0; g < 2; ++g) {
        const int ib = i0 + iw * 8 + g * 4;      // 4 consecutive output rows
        const int kkS = iw * 8 + g * 4;          // = (ib-WIN) - (i0-WIN)
        float b0 = 3e38f, b1 = 3e38f, b2 = 3e38f, b3 = 3e38f;
        float kf = (float)(ib - WIN);
        const float m0 = -2.f * (float)(ib);
        const float m1 = -2.f * (float)(ib + 1);
        const float m2 = -2.f * (float)(ib + 2);
        const float m3 = -2.f * (float)(ib + 3);
        #pragma unroll
        for (int kk = kkS; kk < kkS + 2 * WIN + 4; ++kk) {
            const float hvv = hs[kk * HS_STRIDE + jj];
            b0 = fminf(b0, fmaf(m0, kf, hvv));
            b1 = fminf(b1, fmaf(m1, kf, hvv));
            b2 = fminf(b2, fmaf(m2, kf, hvv));
            b3 = fminf(b3, fmaf(m3, kf, hvv));
            kf += 1.f;
        }
        const int sLo = max(0, ib - WIN);
        const int sHi = min(HW - 1, ib + WIN + 3);
        float bs[4] = {b0, b1, b2, b3};
        #pragma unroll
        for (int w = 0; w < 4; ++w) {
            const int i = ib + w;
            float D2 = (float)(i * i) + bs[w];
            // exactness: any excluded k has (i-k)^2 >= gap^2
            const int dl = i - sLo + 1, dr = sHi + 1 - i;
            const bool need = ((sLo > 0) && (D2 > (float)(dl * dl))) ||
                              ((sHi < HW - 1) && (D2 > (float)(dr * dr)));
            if (need) {  // statistically-dead exact fallback: full column scan
                float bb = 3e38f, k2 = 0.f;
                const float mm = -2.f * (float)i;
                for (int k = 0; k < HW; ++k) {
                    const unsigned gu = gg[k * HW + j0 + jj];
                    const float gf = (gu == 65535u) ? (1e6f - (float)(j0 + jj))
                                                    : (float)gu;
                    bb = fminf(bb, fmaf(mm, k2, fmaf(gf, gf, k2 * k2)));
                    k2 += 1.f;
                }
                D2 = (float)(i * i) + bb;
            }
            const unsigned wbit = (esb[i - i0] >> jj) & 1u;
            lsum += wbit ? sqrtf(D2) : 0.f;
        }
    }

    // reduce: wave shuffle then cross-wave via LDS; plain store per block
    #pragma unroll
    for (int off = 32; off > 0; off >>= 1) lsum += __shfl_down(lsum, off);
    if ((threadIdx.x & 63) == 0) wsum[threadIdx.x >> 6] = lsum;
    __syncthreads();

    const int bid = blockIdx.x + 64 * (blockIdx.y + 8 * blockIdx.z);
    if (threadIdx.x == 0) {
        partial[bid] = wsum[0] + wsum[1] + wsum[2] + wsum[3];
        __threadfence();   // release: partial visible device-wide before count
        // two-level done counters: 16 x fan-in-64, then 1 x fan-in-16.
        int w = 0;
        const unsigned v = atomicAdd(&cnts[bid & 15], 1u);
        if (v == 63u) {
            const unsigned v2 = atomicAdd(&cnts[16], 1u);
            if (v2 == 15u) w = 1;   // exactly one block in the whole grid
        }
        winf = w;                   // ONLY t0 writes (R7 bug: all threads wrote)
    }
    __syncthreads();

    if (winf) {                     // winner block: all 1024 partials are done
        __threadfence();            // acquire: invalidate caches before reads
        const int t = threadIdx.x;
        float s = partial[t] + partial[t + 256] + partial[t + 512] + partial[t + 768];
        #pragma unroll
        for (int off = 32; off > 0; off >>= 1) s += __shfl_down(s, off);
        if ((t & 63) == 0) wsum[t >> 6] = s;
        __syncthreads();
        if (t == 0) {
            const float tot = wsum[0] + wsum[1] + wsum[2] + wsum[3];
            const float loss = tot * (1.f / (2.f * 1024.f * 1024.f));
            out[0] = 1.f / (1.f + expf(-loss));
        }
    }
}

extern "C" void kernel_launch(void* const* d_in, const int* in_sizes, int n_in,
                              void* d_out, int out_size, void* d_ws, size_t ws_size,
                              hipStream_t stream)
{
    const float* preds   = (const float*)d_in[0];
    const float* targets = (const float*)d_in[1];
    float* out = (float*)d_out;

    char* ws = (char*)d_ws;
    unsigned short* gp  = (unsigned short*)ws;            // 2 MB
    unsigned short* gt  = gp + HW * HW;                   // 2 MB
    unsigned short* epb = gt + HW * HW;                   // 128 KB (64 words x 1024 rows)
    unsigned short* etb = epb + 64 * HW;                  // 128 KB
    float* partial = (float*)(etb + 64 * HW);             // 4 KB
    unsigned* cnts = (unsigned*)(partial + 1024);         // 68 B (16 L1 + 1 L2)

    dim3 gA(HW / 4, 2, 1);
    k_rows<<<gA, 256, 0, stream>>>(preds, targets, gp, gt, epb, etb, cnts);

    dim3 gB(HW / 16, HW / RPB, 2);
    k_cols<<<gB, 256, 0, stream>>>(gp, gt, epb, etb, partial, cnts, out);
}

// Round 9
// 74.856 us; speedup vs baseline: 1.2222x; 1.2222x over previous
//
#include <hip/hip_runtime.h>
#include <math.h>

// BoundaryDistanceLoss — H=W=1024 binary masks (float 0/1).
// edges = seg - erode3x3(seg); exact EDT of edges; loss =
// sigmoid((mean(target_edges*pred_dt) + mean(pred_edges*target_dt))/2).
//
// R8->R9: DELETED the done-counter/fence/winner machinery (prime suspect for
// R8's +14us: 1024 device-scope __threadfence + returning atomicAdds; same
// signature as R2's +20us). Back to R5's proven 3-node atomics-free skeleton,
// KEEPING R8's slim IO (u16 g, bit-packed transposed edges) to isolate the
// two variables: ~75us => counters were the regression; ~90us => slim IO is
// guilty and next step is exact-R5 revert.
//
// ws layout: gp (2MB u16) | gt (2MB) | epb (128KB u16) | etb (128KB)
//            | partial (4KB f32)
// g[r][j] = row-distance to nearest edge (65535 => empty row, g=1e6-j)

#define HW 1024
#define RMIN_SENT (1 << 30)
#define WIN 8
#define RPB 128
#define KROWS (RPB + 2 * WIN)   // 144
#define HS_STRIDE 17

// ---------------- Kernel A: edges + row-pass (one row per wave) ----------------
// grid (256, 2), block 256 = 4 waves = 4 rows. Lane owns 16 contiguous cols.
__global__ __launch_bounds__(256)
void k_rows(const float* __restrict__ pred, const float* __restrict__ targ,
            unsigned short* __restrict__ gp, unsigned short* __restrict__ gt,
            unsigned short* __restrict__ epb, unsigned short* __restrict__ etb)
{
    const int t    = threadIdx.x;
    const int lane = t & 63;
    const int wv   = t >> 6;
    const int r    = blockIdx.x * 4 + wv;     // row 0..1023
    const int m    = blockIdx.y;              // image 0=pred 1=target
    const float* __restrict__ seg = m ? targ : pred;
    unsigned short* __restrict__ gout = m ? gt : gp;
    unsigned short* __restrict__ ebout = m ? etb : epb;

    const int c0 = lane * 16;                 // first global col of this lane

    float cs[16], cm[16], cp[16];
    #pragma unroll
    for (int q = 0; q < 4; ++q)
        *(float4*)&cs[q * 4] = *(const float4*)&seg[r * HW + c0 + q * 4];
    #pragma unroll
    for (int q = 0; q < 4; ++q) {
        *(float4*)&cm[q * 4] = make_float4(0.f, 0.f, 0.f, 0.f);
        *(float4*)&cp[q * 4] = make_float4(0.f, 0.f, 0.f, 0.f);
    }
    if (r > 0) {
        #pragma unroll
        for (int q = 0; q < 4; ++q)
            *(float4*)&cm[q * 4] = *(const float4*)&seg[(r - 1) * HW + c0 + q * 4];
    }
    if (r < HW - 1) {
        #pragma unroll
        for (int q = 0; q < 4; ++q)
            *(float4*)&cp[q * 4] = *(const float4*)&seg[(r + 1) * HW + c0 + q * 4];
    }

    // bitmasks over the lane's 16 columns
    unsigned s_bits = 0, va_bits = 0;
    #pragma unroll
    for (int x = 0; x < 16; ++x) {
        const unsigned s  = (cs[x] != 0.f) ? 1u : 0u;
        const unsigned va = (cs[x] != 0.f && cm[x] != 0.f && cp[x] != 0.f) ? 1u : 0u;
        s_bits  |= s  << x;
        va_bits |= va << x;
    }

    // neighbor bits across lanes (image border -> 0, matches zero padding)
    const unsigned vprev = __shfl_up(va_bits, 1);
    const unsigned vnext = __shfl_down(va_bits, 1);
    const unsigned lbit = (lane == 0)  ? 0u : ((vprev >> 15) & 1u);
    const unsigned rbit = (lane == 63) ? 0u : (vnext & 1u);

    // eroded_x = va_{x-1} & va_x & va_{x+1} via an 18-bit window
    const unsigned w18 = (va_bits << 1) | lbit | (rbit << 17);
    const unsigned eroded = w18 & (w18 >> 1) & (w18 >> 2);
    const unsigned edge = s_bits & ~eroded & 0xFFFFu;

    // edge bits: transposed layout ebout[wordcol*1024 + r] for coalesced consume
    ebout[lane * HW + r] = (unsigned short)edge;

    // lane aggregates: last/first set feature col in this lane
    const int lane_last  = edge ? (c0 + 31 - __clz(edge)) : -1;
    const int lane_first = edge ? (c0 + __ffs(edge) - 1)  : RMIN_SENT;

    // wave scans (inclusive), then exclusive carries
    int Li = lane_last;
    #pragma unroll
    for (int off = 1; off < 64; off <<= 1) {
        const int v = __shfl_up(Li, off);
        if (lane >= off) Li = max(Li, v);
    }
    int Ri = lane_first;
    #pragma unroll
    for (int off = 1; off < 64; off <<= 1) {
        const int v = __shfl_down(Ri, off);
        if (lane + off < 64) Ri = min(Ri, v);
    }
    int carryL = __shfl_up(Li, 1);   if (lane == 0)  carryL = -1;
    int carryR = __shfl_down(Ri, 1); if (lane == 63) carryR = RMIN_SENT;

    // per-column nearest feature; g as u16 (65535 == empty row => g = 1e6 - j)
    unsigned short gv[16];
    #pragma unroll
    for (int x = 0; x < 16; ++x) {
        const unsigned ble = edge & ((2u << x) - 1u);   // bits 0..x
        const int L = ble ? (c0 + 31 - __clz(ble)) : carryL;
        const unsigned bge = edge >> x;                 // bits x..15
        const int R = bge ? (c0 + x + __ffs(bge) - 1) : carryR;
        const int j = c0 + x;
        int g;
        if (L < 0 && R >= RMIN_SENT)      g = 65535;          // empty row sentinel
        else if (L < 0)                   g = R - j;
        else if (R >= RMIN_SENT)          g = j - L;
        else                              g = min(j - L, R - j);
        gv[x] = (unsigned short)g;
    }
    unsigned wpk[8];
    #pragma unroll
    for (int k2 = 0; k2 < 8; ++k2)
        wpk[k2] = (unsigned)gv[2 * k2] | ((unsigned)gv[2 * k2 + 1] << 16);
    uint4 st0, st1;
    st0.x = wpk[0]; st0.y = wpk[1]; st0.z = wpk[2]; st0.w = wpk[3];
    st1.x = wpk[4]; st1.y = wpk[5]; st1.z = wpk[6]; st1.w = wpk[7];
    *(uint4*)&gout[r * HW + c0]     = st0;
    *(uint4*)&gout[r * HW + c0 + 8] = st1;
}

// ------------- Kernel B: column EDT (windowed, exact) + per-block partial -------
// grid (64 col-tiles, 8 row-chunks, 2 images) = 1024 blocks, block 256.
__global__ __launch_bounds__(256)
void k_cols(const unsigned short* __restrict__ gp, const unsigned short* __restrict__ gt,
            const unsigned short* __restrict__ epb, const unsigned short* __restrict__ etb,
            float* __restrict__ partial)
{
    const int j0 = blockIdx.x * 16;
    const int i0 = blockIdx.y * RPB;
    const int m  = blockIdx.z;
    const unsigned short* __restrict__ gg = m ? gt : gp;
    const unsigned short* __restrict__ ewb = m ? epb : etb;  // OTHER image's edges

    __shared__ float hs[KROWS * HS_STRIDE];
    __shared__ unsigned short esb[RPB];
    __shared__ float wsum[4];

    // stage h = g^2 + k^2 (g from u16; sentinel -> g = 1e6 - j, ref-exact)
    for (int idx = threadIdx.x; idx < KROWS * 16; idx += 256) {
        const int kk = idx >> 4, jc = idx & 15;
        const int gk = i0 - WIN + kk;
        float v = 1e30f;
        if ((unsigned)gk < (unsigned)HW) {
            const unsigned gu = gg[gk * HW + j0 + jc];
            float gf = (gu == 65535u) ? (1e6f - (float)(j0 + jc)) : (float)gu;
            v = fmaf(gf, gf, (float)(gk * gk));
        }
        hs[kk * HS_STRIDE + jc] = v;
    }
    if (threadIdx.x < RPB)
        esb[threadIdx.x] = ewb[(j0 >> 4) * HW + i0 + threadIdx.x];
    __syncthreads();

    const int jj = threadIdx.x & 15;
    const int iw = threadIdx.x >> 4;   // 0..15, each owns 8 rows
    float lsum = 0.f;

    #pragma unroll
    for (int g = 0; g < 2; ++g) {
        const int ib = i0 + iw * 8 + g * 4;      // 4 consecutive output rows
        const int kkS = iw * 8 + g * 4;          // = (ib-WIN) - (i0-WIN)
        float b0 = 3e38f, b1 = 3e38f, b2 = 3e38f, b3 = 3e38f;
        float kf = (float)(ib - WIN);
        const float m0 = -2.f * (float)(ib);
        const float m1 = -2.f * (float)(ib + 1);
        const float m2 = -2.f * (float)(ib + 2);
        const float m3 = -2.f * (float)(ib + 3);
        #pragma unroll
        for (int kk = kkS; kk < kkS + 2 * WIN + 4; ++kk) {
            const float hvv = hs[kk * HS_STRIDE + jj];
            b0 = fminf(b0, fmaf(m0, kf, hvv));
            b1 = fminf(b1, fmaf(m1, kf, hvv));
            b2 = fminf(b2, fmaf(m2, kf, hvv));
            b3 = fminf(b3, fmaf(m3, kf, hvv));
            kf += 1.f;
        }
        const int sLo = max(0, ib - WIN);
        const int sHi = min(HW - 1, ib + WIN + 3);
        float bs[4] = {b0, b1, b2, b3};
        #pragma unroll
        for (int w = 0; w < 4; ++w) {
            const int i = ib + w;
            float D2 = (float)(i * i) + bs[w];
            // exactness: any excluded k has (i-k)^2 >= gap^2
            const int dl = i - sLo + 1, dr = sHi + 1 - i;
            const bool need = ((sLo > 0) && (D2 > (float)(dl * dl))) ||
                              ((sHi < HW - 1) && (D2 > (float)(dr * dr)));
            if (need) {  // statistically-dead exact fallback: full column scan
                float bb = 3e38f, k2 = 0.f;
                const float mm = -2.f * (float)i;
                for (int k = 0; k < HW; ++k) {
                    const unsigned gu = gg[k * HW + j0 + jj];
                    const float gf = (gu == 65535u) ? (1e6f - (float)(j0 + jj))
                                                    : (float)gu;
                    bb = fminf(bb, fmaf(mm, k2, fmaf(gf, gf, k2 * k2)));
                    k2 += 1.f;
                }
                D2 = (float)(i * i) + bb;
            }
            const unsigned wbit = (esb[i - i0] >> jj) & 1u;
            lsum += wbit ? sqrtf(D2) : 0.f;
        }
    }

    // reduce: wave shuffle then cross-wave via LDS; ONE plain store per block
    #pragma unroll
    for (int off = 32; off > 0; off >>= 1) lsum += __shfl_down(lsum, off);
    if ((threadIdx.x & 63) == 0) wsum[threadIdx.x >> 6] = lsum;
    __syncthreads();
    if (threadIdx.x == 0) {
        const int bid = blockIdx.x + 64 * (blockIdx.y + 8 * blockIdx.z);
        partial[bid] = wsum[0] + wsum[1] + wsum[2] + wsum[3];
    }
}

// ---------------- Kernel C: reduce 1024 partials + sigmoid ----------------
__global__ __launch_bounds__(256)
void k_fin(const float* __restrict__ partial, float* __restrict__ out)
{
    const int t = threadIdx.x;
    float s = partial[t] + partial[t + 256] + partial[t + 512] + partial[t + 768];
    #pragma unroll
    for (int off = 32; off > 0; off >>= 1) s += __shfl_down(s, off);
    __shared__ float w[4];
    if ((t & 63) == 0) w[t >> 6] = s;
    __syncthreads();
    if (t == 0) {
        const float tot = w[0] + w[1] + w[2] + w[3];
        const float loss = tot * (1.f / (2.f * 1024.f * 1024.f));
        out[0] = 1.f / (1.f + expf(-loss));
    }
}

extern "C" void kernel_launch(void* const* d_in, const int* in_sizes, int n_in,
                              void* d_out, int out_size, void* d_ws, size_t ws_size,
                              hipStream_t stream)
{
    const float* preds   = (const float*)d_in[0];
    const float* targets = (const float*)d_in[1];
    float* out = (float*)d_out;

    char* ws = (char*)d_ws;
    unsigned short* gp  = (unsigned short*)ws;            // 2 MB
    unsigned short* gt  = gp + HW * HW;                   // 2 MB
    unsigned short* epb = gt + HW * HW;                   // 128 KB (64 words x 1024 rows)
    unsigned short* etb = epb + 64 * HW;                  // 128 KB
    float* partial = (float*)(etb + 64 * HW);             // 4 KB

    dim3 gA(HW / 4, 2, 1);
    k_rows<<<gA, 256, 0, stream>>>(preds, targets, gp, gt, epb, etb);

    dim3 gB(HW / 16, HW / RPB, 2);
    k_cols<<<gB, 256, 0, stream>>>(gp, gt, epb, etb, partial);

    k_fin<<<1, 256, 0, stream>>>(partial, out);
}